// Round 14
// baseline (155.248 us; speedup 1.0000x reference)
//
#include <hip/hip_runtime.h>
#include <hip/hip_bf16.h>
#include <math.h>

#define NNODE   17
#define HH      32
#define BTOT    131072
#define AHSTR   20      // floats per Ah row (80 B: 16B-aligned)
#define H1STR   40      // shorts per h1dT/g row (80 B; 2-way bank aliasing = free)
#define ZSTR    20      // shorts per zl out1-row (40 B; 8B-aligned uint2 packs)
#define GSTRIDE 8704    // shorts per 16-item h2 group: 17*4*16*8

typedef __attribute__((ext_vector_type(8))) short short8v;
typedef __attribute__((ext_vector_type(4))) float f32x4;

__device__ __forceinline__ float elu(float a) {
    return (a > 0.f) ? a : (__expf(a) - 1.0f);
}
__device__ __forceinline__ short bf16s(float x) {
    __hip_bfloat16 h = __float2bfloat16(x);
    return *reinterpret_cast<short*>(&h);
}
__device__ __forceinline__ float bfround(float x) {
    return __bfloat162float(__float2bfloat16(x));
}
__device__ __forceinline__ float blo(unsigned u){ return __uint_as_float(u << 16); }
__device__ __forceinline__ float bhi(unsigned u){ return __uint_as_float(u & 0xFFFF0000u); }
__device__ __forceinline__ unsigned pack2(float a, float b) {
    return ((unsigned)(unsigned short)bf16s(a)) | (((unsigned)(unsigned short)bf16s(b)) << 16);
}
// nontemporal (evict-first) load: keep one-shot streams (adj) out of L3 so h2g stays resident
__device__ __forceinline__ float ntload(const float* p) {
    return __builtin_nontemporal_load(p);
}

// h2g tiled layout: item group g16=item>>4, i16=item&15
//   offset_shorts(item,n,chan) = g16*GSTRIDE + ((n*4 + (chan>>3))*16 + i16)*8 + (chan&7)
// pass2 per-n wave load: lanes (col,grp) -> base + l64*16B (fully contiguous 1024B)

// ---------------------------------------------------------------- PASS 1 (R12 structure, tiled h2g stores)
struct __align__(16) SlotB {
    float Ah[NNODE * AHSTR];
    float dinv[20];
    float xd[20];
    float ag[20];
    __hip_bfloat16 h1dT[32 * H1STR];
    __hip_bfloat16 g[NNODE * H1STR + 8];
};

__global__ __launch_bounds__(256) void pass1_kernel(
    const float* __restrict__ x_str, const float* __restrict__ adj,
    const float* __restrict__ W1, const float* __restrict__ b1,
    const float* __restrict__ W2, const float* __restrict__ b2,
    __hip_bfloat16* __restrict__ h2g, float* __restrict__ gstat)
{
    __shared__ SlotB sa[8];
    __shared__ float statb[4 * 34];

    const int tid  = threadIdx.x;
    const int slot = tid >> 5;
    const int lane = tid & 31;
    const int l64  = tid & 63;
    const int w    = tid >> 6;
    SlotB& sm = sa[slot];

    const float W1o = W1[lane], b1o = b1[lane];

    const int col = l64 & 15;
    const int grp = l64 >> 4;
    short8v wh0, wl0, wh1, wl1;
    #pragma unroll
    for (int j = 0; j < 8; ++j) {
        float w0 = W2[(8 * grp + j) * 32 + col];
        float w1 = W2[(8 * grp + j) * 32 + col + 16];
        wh0[j] = bf16s(w0); wl0[j] = bf16s(w0 - bfround(w0));
        wh1[j] = bf16s(w1); wl1[j] = bf16s(w1 - bfround(w1));
    }
    const float b2c0 = b2[col];
    const float b2c1 = b2[col + 16];

    float s4[4] = {0.f, 0.f, 0.f, 0.f};
    float q4[4] = {0.f, 0.f, 0.f, 0.f};
    float s16 = 0.f, q16 = 0.f;

    for (int z = lane; z < NNODE * AHSTR; z += 32) sm.Ah[z] = 0.f;
    {
        unsigned* hz = reinterpret_cast<unsigned*>(sm.h1dT);
        for (int z = lane; z < 16 * H1STR; z += 32) hz[z] = 0u;
    }

    const int base = blockIdx.x * 64;

    float rbuf[10];
    float rxs;
    {
        const size_t aoff0 = (size_t)(base + slot) * (NNODE * NNODE);
        #pragma unroll
        for (int j = 0; j < 9; ++j) rbuf[j] = ntload(&adj[aoff0 + j * 32 + lane]);
        rbuf[9] = (lane == 0) ? ntload(&adj[aoff0 + 288]) : 0.f;
        rxs = (lane < NNODE) ? ntload(&x_str[(size_t)(base + slot) * NNODE + lane]) : 0.f;
    }

    for (int it = 0; it < 8; ++it) {
        const int item = base + it * 8 + slot;

        #pragma unroll
        for (int j = 0; j < 10; ++j) {
            const int k2 = j * 32 + lane;
            if (j < 9 || lane == 0) {
                int n = (k2 * 241) >> 12;
                int m = k2 - n * NNODE;
                sm.Ah[n * AHSTR + m] = (n == m) ? rbuf[j] + 1.0f : rbuf[j];
            }
        }
        const float xs = rxs;

        if (it < 7) {
            const size_t aoffn = (size_t)(item + 8) * (NNODE * NNODE);
            #pragma unroll
            for (int j = 0; j < 9; ++j) rbuf[j] = ntload(&adj[aoffn + j * 32 + lane]);
            rbuf[9] = (lane == 0) ? ntload(&adj[aoffn + 288]) : 0.f;
            rxs = (lane < NNODE) ? ntload(&x_str[(size_t)(item + 8) * NNODE + lane]) : 0.f;
        }

        float row[NNODE];
        float di = 0.f;
        if (lane < NNODE) {
            const float4* rp = reinterpret_cast<const float4*>(&sm.Ah[lane * AHSTR]);
            float4 a0 = rp[0], a1 = rp[1], a2 = rp[2], a3 = rp[3];
            row[0]=a0.x; row[1]=a0.y; row[2]=a0.z; row[3]=a0.w;
            row[4]=a1.x; row[5]=a1.y; row[6]=a1.z; row[7]=a1.w;
            row[8]=a2.x; row[9]=a2.y; row[10]=a2.z; row[11]=a2.w;
            row[12]=a3.x; row[13]=a3.y; row[14]=a3.z; row[15]=a3.w;
            row[16] = sm.Ah[lane * AHSTR + 16];
            float d = 0.f;
            #pragma unroll
            for (int m = 0; m < NNODE; ++m) d += row[m];
            di = (d > 0.f) ? rsqrtf(d) : 0.f;
            sm.dinv[lane] = di;
            sm.xd[lane]   = di * xs;
        }
        if (lane < NNODE) {
            const float4* xp = reinterpret_cast<const float4*>(sm.xd);
            float4 x0 = xp[0], x1 = xp[1], x2 = xp[2], x3 = xp[3];
            float a;
            a  = row[0]*x0.x + row[1]*x0.y + row[2]*x0.z + row[3]*x0.w;
            a += row[4]*x1.x + row[5]*x1.y + row[6]*x1.z + row[7]*x1.w;
            a += row[8]*x2.x + row[9]*x2.y + row[10]*x2.z + row[11]*x2.w;
            a += row[12]*x3.x + row[13]*x3.y + row[14]*x3.z + row[15]*x3.w;
            a += row[16] * sm.xd[16];
            sm.ag[lane] = a * di;
        }
        float h1d[NNODE];
        {
            const float4* dp = reinterpret_cast<const float4*>(sm.dinv);
            const float4* ap = reinterpret_cast<const float4*>(sm.ag);
            float dv[NNODE], av[NNODE];
            #pragma unroll
            for (int q = 0; q < 4; ++q) {
                float4 d4 = dp[q], a4 = ap[q];
                dv[4*q]=d4.x; dv[4*q+1]=d4.y; dv[4*q+2]=d4.z; dv[4*q+3]=d4.w;
                av[4*q]=a4.x; av[4*q+1]=a4.y; av[4*q+2]=a4.z; av[4*q+3]=a4.w;
            }
            dv[16] = sm.dinv[16]; av[16] = sm.ag[16];
            #pragma unroll
            for (int m = 0; m < NNODE; ++m) {
                float a = av[m] * W1o + b1o;
                h1d[m] = dv[m] * elu(a);
            }
        }
        {
            uint2* hw2 = reinterpret_cast<uint2*>(&sm.h1dT[lane * H1STR]);
            #pragma unroll
            for (int p = 0; p < 4; ++p) {
                uint2 v;
                v.x = pack2(h1d[4 * p],     h1d[4 * p + 1]);
                v.y = pack2(h1d[4 * p + 2], h1d[4 * p + 3]);
                hw2[p] = v;
            }
            reinterpret_cast<short*>(sm.h1dT)[lane * H1STR + 16] = bf16s(h1d[16]);
        }
        {
            const float4* rp16 = reinterpret_cast<const float4*>(&sm.Ah[16 * AHSTR]);
            float4 b0 = rp16[0], b1v = rp16[1], b2v = rp16[2], b3 = rp16[3];
            float a16;
            a16  = b0.x*h1d[0]  + b0.y*h1d[1]  + b0.z*h1d[2]  + b0.w*h1d[3];
            a16 += b1v.x*h1d[4] + b1v.y*h1d[5] + b1v.z*h1d[6] + b1v.w*h1d[7];
            a16 += b2v.x*h1d[8] + b2v.y*h1d[9] + b2v.z*h1d[10]+ b2v.w*h1d[11];
            a16 += b3.x*h1d[12] + b3.y*h1d[13] + b3.z*h1d[14] + b3.w*h1d[15];
            a16 += sm.Ah[16 * AHSTR + 16] * h1d[16];
            reinterpret_cast<short*>(sm.g)[16 * H1STR + lane] =
                bf16s(a16 * sm.dinv[16]);
        }

        #pragma unroll
        for (int i = 0; i < 2; ++i) {
            SlotB& si = sa[2 * w + i];
            const float dn = si.dinv[col];
            short8v ah;
            if (grp < 3) {
                float4 f0 = *reinterpret_cast<const float4*>(&si.Ah[col * AHSTR + grp * 8]);
                float4 f1 = *reinterpret_cast<const float4*>(&si.Ah[col * AHSTR + grp * 8 + 4]);
                float vv[8] = {f0.x, f0.y, f0.z, f0.w, f1.x, f1.y, f1.z, f1.w};
                #pragma unroll
                for (int j = 0; j < 8; ++j) ah[j] = bf16s(dn * vv[j]);
            } else {
                #pragma unroll
                for (int j = 0; j < 8; ++j) ah[j] = 0;
            }
            #pragma unroll
            for (int h = 0; h < 2; ++h) {
                short8v bq = *reinterpret_cast<const short8v*>(
                    &si.h1dT[(col + 16 * h) * H1STR + grp * 8]);
                f32x4 c = {0.f, 0.f, 0.f, 0.f};
                c = __builtin_amdgcn_mfma_f32_16x16x32_bf16(ah, bq, c, 0, 0, 0);
                #pragma unroll
                for (int r = 0; r < 4; ++r) {
                    reinterpret_cast<short*>(si.g)[(grp * 4 + r) * H1STR + col + 16 * h] =
                        bf16s(c[r]);
                }
            }
        }

        // ==== phase B: h2 = elu(agg2 @ W2 + b2) via intra-wave MFMA + stats
        //      tiled h2g stores: offset = g16*GSTRIDE + ((n*4+(chan>>3))*16+i16)*8 + (chan&7)
        #pragma unroll
        for (int i = 0; i < 2; ++i) {
            const int itm = base + it * 8 + 2 * w + i;
            short8v a = *reinterpret_cast<const short8v*>(
                &sa[2 * w + i].g[col * H1STR + grp * 8]);
            f32x4 c0 = {b2c0, b2c0, b2c0, b2c0};
            f32x4 c1 = {b2c1, b2c1, b2c1, b2c1};
            c0 = __builtin_amdgcn_mfma_f32_16x16x32_bf16(a, wh0, c0, 0, 0, 0);
            c0 = __builtin_amdgcn_mfma_f32_16x16x32_bf16(a, wl0, c0, 0, 0, 0);
            c1 = __builtin_amdgcn_mfma_f32_16x16x32_bf16(a, wh1, c1, 0, 0, 0);
            c1 = __builtin_amdgcn_mfma_f32_16x16x32_bf16(a, wl1, c1, 0, 0, 0);
            const size_t gb = (size_t)(itm >> 4) * GSTRIDE
                            + (size_t)(itm & 15) * 8 + (col & 7)
                            + (size_t)(col >> 3) * 128;
            #pragma unroll
            for (int r = 0; r < 4; ++r) {
                float h0 = elu(c0[r]);
                float h1 = elu(c1[r]);
                const size_t o0 = gb + (size_t)((grp * 4 + r) * 4) * 128;
                h2g[o0]       = __float2bfloat16(h0);
                h2g[o0 + 256] = __float2bfloat16(h1);   // chan+16 -> +2*128
                s4[r] += h0 + h1;
                q4[r] += h0 * h0 + h1 * h1;
            }
        }
        {
            const int ii = (l64 & 15) & 1;
            short8v a = *reinterpret_cast<const short8v*>(
                &sa[2 * w + ii].g[16 * H1STR + grp * 8]);
            f32x4 c0 = {b2c0, b2c0, b2c0, b2c0};
            f32x4 c1 = {b2c1, b2c1, b2c1, b2c1};
            c0 = __builtin_amdgcn_mfma_f32_16x16x32_bf16(a, wh0, c0, 0, 0, 0);
            c0 = __builtin_amdgcn_mfma_f32_16x16x32_bf16(a, wl0, c0, 0, 0, 0);
            c1 = __builtin_amdgcn_mfma_f32_16x16x32_bf16(a, wh1, c1, 0, 0, 0);
            c1 = __builtin_amdgcn_mfma_f32_16x16x32_bf16(a, wl1, c1, 0, 0, 0);
            if (grp == 0) {
                #pragma unroll
                for (int r = 0; r < 2; ++r) {
                    float h0 = elu(c0[r]);
                    float h1 = elu(c1[r]);
                    const int itm2 = base + it * 8 + 2 * w + r;
                    const size_t o = (size_t)(itm2 >> 4) * GSTRIDE
                                   + (size_t)((16 * 4 + (col >> 3)) * 16 + (itm2 & 15)) * 8
                                   + (col & 7);
                    h2g[o]       = __float2bfloat16(h0);
                    h2g[o + 256] = __float2bfloat16(h1);
                    s16 += h0 + h1;
                    q16 += h0 * h0 + h1 * h1;
                }
            }
        }
    }

    #pragma unroll
    for (int m = 1; m <= 8; m <<= 1) {
        #pragma unroll
        for (int r = 0; r < 4; ++r) {
            s4[r] += __shfl_xor(s4[r], m, 64);
            q4[r] += __shfl_xor(q4[r], m, 64);
        }
        s16 += __shfl_xor(s16, m, 64);
        q16 += __shfl_xor(q16, m, 64);
    }
    if ((l64 & 15) == 0) {
        #pragma unroll
        for (int r = 0; r < 4; ++r) {
            const int n = grp * 4 + r;
            statb[w * 34 + n]         = s4[r];
            statb[w * 34 + NNODE + n] = q4[r];
        }
        if (grp == 0) {
            statb[w * 34 + 16]         = s16;
            statb[w * 34 + NNODE + 16] = q16;
        }
    }
    __syncthreads();
    if (tid < 34) {
        float s = statb[tid] + statb[34 + tid] + statb[68 + tid] + statb[102 + tid];
        unsafeAtomicAdd(&gstat[tid], s);
    }
}

// ---------------------------------------------------------------- PASS 2 (MFMA head; tiled coalesced h2g reads)
__global__ __launch_bounds__(256) void pass2_kernel(
    const __hip_bfloat16* __restrict__ h2g,
    const float* __restrict__ x_raw, const float* __restrict__ x_cov,
    const float* __restrict__ age,
    const float* __restrict__ gamma, const float* __restrict__ beta,
    const float* __restrict__ Wr1, const float* __restrict__ br1,
    const float* __restrict__ Wr2, const float* __restrict__ br2,
    const float* __restrict__ Wr3, const float* __restrict__ br3,
    const float* __restrict__ gstat, float* __restrict__ out)
{
    __shared__ short8v wf1[8][64];                  // Wr1 hi-frags (8 KB)
    __shared__ short8v wf2[8][64];                  // Wr2^T hi/lo  (8 KB)
    __shared__ __hip_bfloat16 zl[4][64 * ZSTR];     // z bf16, wave-private (10 KB)
    __shared__ float   s17[18];

    const int tid = threadIdx.x;
    const int w   = tid >> 6;
    const int l   = tid & 63;
    const int col = l & 15;
    const int g   = l >> 4;
    const int ibase = blockIdx.x * 64;
    const int wb    = ibase + w * 16;
    const int item  = wb + col;

    if (tid == 0) {
        const float invBH = 1.0f / ((float)BTOT * (float)HH);
        float Cs = 0.f;
        #pragma unroll
        for (int n = 0; n < NNODE; ++n) {
            float mean = gstat[n] * invBH;
            float var  = gstat[NNODE + n] * invBH - mean * mean;
            float sc   = gamma[n] * rsqrtf(var + 1e-5f);
            s17[n] = sc * (1.0f / (float)NNODE);
            Cs += beta[n] - mean * sc;
        }
        s17[NNODE] = Cs * (1.0f / (float)NNODE);
    }

    for (int idx = tid; idx < 8 * 64; idx += 256) {
        int fid = idx >> 6, tl = idx & 63;
        int kst = fid >> 2, nt = fid & 3;
        int tc = tl & 15, tg = tl >> 4;
        short8v v;
        #pragma unroll
        for (int j = 0; j < 8; ++j) {
            int k = kst * 32 + tg * 8 + j;
            float f = (k < 53) ? Wr1[k * 64 + nt * 16 + tc] : 0.f;
            v[j] = bf16s(f);
        }
        wf1[fid][tl] = v;
    }
    for (int idx = tid; idx < 8 * 64; idx += 256) {
        int fid = idx >> 6, tl = idx & 63;
        int kst = fid >> 2, mt = (fid >> 1) & 1, hl = fid & 1;
        int tc = tl & 15, tg = tl >> 4;
        short8v v;
        #pragma unroll
        for (int j = 0; j < 8; ++j) {
            int k = kst * 32 + tg * 8 + j;
            float f = Wr2[k * 32 + mt * 16 + tc];
            v[j] = hl ? bf16s(f - bfround(f)) : bf16s(f);
        }
        wf2[fid][tl] = v;
    }
    __syncthreads();

    // ---- emb: 17 fully-coalesced wave loads (lane addr = base + l64*16B)
    float emb[8];
    const float cst = s17[NNODE];
    #pragma unroll
    for (int j = 0; j < 8; ++j) emb[j] = cst;
    const __hip_bfloat16* hp = h2g + (size_t)(wb >> 4) * GSTRIDE + (size_t)l * 8;
    #pragma unroll
    for (int n = 0; n < NNODE; ++n) {
        uint4 v = *reinterpret_cast<const uint4*>(hp + (size_t)n * 512);
        float sn = s17[n];
        emb[0] += sn * blo(v.x); emb[1] += sn * bhi(v.x);
        emb[2] += sn * blo(v.y); emb[3] += sn * bhi(v.y);
        emb[4] += sn * blo(v.z); emb[5] += sn * bhi(v.z);
        emb[6] += sn * blo(v.w); emb[7] += sn * bhi(v.w);
    }

    // ---- raw tail loaded per-lane from global
    float tail[8];
    if (g < 2) {
        const float* xr = x_raw + (size_t)item * 17 + g * 8;
        #pragma unroll
        for (int j = 0; j < 8; ++j) tail[j] = xr[j];
    } else if (g == 2) {
        tail[0] = x_raw[(size_t)item * 17 + 16];
        tail[1] = x_cov[(size_t)item * 3 + 0];
        tail[2] = x_cov[(size_t)item * 3 + 1];
        tail[3] = x_cov[(size_t)item * 3 + 2];
        tail[4] = age[item];
        tail[5] = 0.f; tail[6] = 0.f; tail[7] = 0.f;
    } else {
        #pragma unroll
        for (int j = 0; j < 8; ++j) tail[j] = 0.f;
    }

    short8v a0h, a0l, a1h, a1l;
    #pragma unroll
    for (int j = 0; j < 8; ++j) {
        float f = emb[j];
        a0h[j] = bf16s(f); a0l[j] = bf16s(f - bfround(f));
        float f1 = tail[j];
        a1h[j] = bf16s(f1); a1l[j] = bf16s(f1 - bfround(f1));
    }

    f32x4 C1[4];
    #pragma unroll
    for (int nt = 0; nt < 4; ++nt) {
        float b = br1[nt * 16 + col];
        C1[nt] = (f32x4){b, b, b, b};
        C1[nt] = __builtin_amdgcn_mfma_f32_16x16x32_bf16(a0h, wf1[nt    ][l], C1[nt], 0, 0, 0);
        C1[nt] = __builtin_amdgcn_mfma_f32_16x16x32_bf16(a0l, wf1[nt    ][l], C1[nt], 0, 0, 0);
        C1[nt] = __builtin_amdgcn_mfma_f32_16x16x32_bf16(a1h, wf1[4 + nt][l], C1[nt], 0, 0, 0);
        C1[nt] = __builtin_amdgcn_mfma_f32_16x16x32_bf16(a1l, wf1[4 + nt][l], C1[nt], 0, 0, 0);
    }
    #pragma unroll
    for (int nt = 0; nt < 4; ++nt) {
        uint2 v;
        v.x = pack2(fmaxf(C1[nt][0], 0.f), fmaxf(C1[nt][1], 0.f));
        v.y = pack2(fmaxf(C1[nt][2], 0.f), fmaxf(C1[nt][3], 0.f));
        *reinterpret_cast<uint2*>(&zl[w][(nt * 16 + col) * ZSTR + g * 4]) = v;
    }

    f32x4 C2[2];
    #pragma unroll
    for (int mt = 0; mt < 2; ++mt)
        C2[mt] = (f32x4){br2[mt*16 + g*4], br2[mt*16 + g*4 + 1],
                         br2[mt*16 + g*4 + 2], br2[mt*16 + g*4 + 3]};
    #pragma unroll
    for (int kst = 0; kst < 2; ++kst) {
        short8v bh;
        #pragma unroll
        for (int j = 0; j < 8; ++j)
            bh[j] = reinterpret_cast<const short*>(zl[w])[(kst * 32 + g * 8 + j) * ZSTR + col];
        #pragma unroll
        for (int mt = 0; mt < 2; ++mt) {
            C2[mt] = __builtin_amdgcn_mfma_f32_16x16x32_bf16(wf2[kst*4 + mt*2    ][l], bh, C2[mt], 0, 0, 0);
            C2[mt] = __builtin_amdgcn_mfma_f32_16x16x32_bf16(wf2[kst*4 + mt*2 + 1][l], bh, C2[mt], 0, 0, 0);
        }
    }

    float sum = 0.f;
    #pragma unroll
    for (int mt = 0; mt < 2; ++mt)
        #pragma unroll
        for (int r = 0; r < 4; ++r)
            sum += fmaxf(C2[mt][r], 0.f) * Wr3[mt * 16 + g * 4 + r];
    sum += __shfl_xor(sum, 16, 64);
    sum += __shfl_xor(sum, 32, 64);
    if (l < 16)
        out[wb + l] = 1.0f / (1.0f + __expf(-(sum + br3[0])));
}

// ---------------------------------------------------------------- fallback (round-0, passing)
struct __align__(16) SlotMem {
    float Ah[NNODE][20];
    float dinv[20];
    float xd[20];
    float ex[32];
    float c[56];
    float z[64];
};

template<int PASS>
__global__ __launch_bounds__(256) void gcn_fb_kernel(
    const float* __restrict__ x_str, const float* __restrict__ x_raw,
    const float* __restrict__ adj,   const float* __restrict__ x_cov,
    const float* __restrict__ age,
    const float* __restrict__ W1, const float* __restrict__ b1,
    const float* __restrict__ W2, const float* __restrict__ b2,
    const float* __restrict__ gamma, const float* __restrict__ beta,
    const float* __restrict__ Wr1, const float* __restrict__ br1,
    const float* __restrict__ Wr2, const float* __restrict__ br2,
    const float* __restrict__ Wr3, const float* __restrict__ br3,
    float* __restrict__ gstat, float* __restrict__ out)
{
    __shared__ SlotMem slots[8];
    __shared__ __align__(16) float hw[(PASS == 2) ? 5504 : 1];
    __shared__ float s17[(PASS == 2) ? 18 : 1];
    __shared__ float statb[(PASS == 1) ? 4 * 34 : 1];

    const int tid  = threadIdx.x;
    const int slot = tid >> 5;
    const int lane = tid & 31;
    SlotMem& sm = slots[slot];

    const float W1o = W1[lane];
    const float b1o = b1[lane];
    const float b2o = b2[lane];
    float W2col[HH];
    #pragma unroll
    for (int k = 0; k < HH; ++k) W2col[k] = W2[k * HH + lane];

    float Wr3o = 0.f, br2o = 0.f, br3v = 0.f;
    if constexpr (PASS == 2) {
        Wr3o = Wr3[lane];
        br2o = br2[lane];
        br3v = br3[0];
        for (int t = tid; t < 5504; t += 256) {
            float v;
            if (t < 3392) {
                int i = t >> 6, r = t & 63;
                v = Wr1[i * 64 + ((r & 1) << 5) + (r >> 1)];
            } else if (t < 3456) {
                v = br1[t - 3392];
            } else {
                v = Wr2[t - 3456];
            }
            hw[t] = v;
        }
        if (tid == 0) {
            const float invBH = 1.0f / ((float)BTOT * (float)HH);
            float Cs = 0.f;
            #pragma unroll
            for (int n = 0; n < NNODE; ++n) {
                float mean = gstat[n] * invBH;
                float var  = gstat[NNODE + n] * invBH - mean * mean;
                float sc   = gamma[n] * rsqrtf(var + 1e-5f);
                s17[n] = sc * (1.0f / (float)NNODE);
                Cs += beta[n] - mean * sc;
            }
            s17[NNODE] = Cs * (1.0f / (float)NNODE);
        }
        __syncthreads();
    }

    float psum[NNODE], psq[NNODE];
    if constexpr (PASS == 1) {
        #pragma unroll
        for (int n = 0; n < NNODE; ++n) { psum[n] = 0.f; psq[n] = 0.f; }
    }

    const int base = blockIdx.x * 64;
    for (int it = 0; it < 8; ++it) {
        const int item = base + it * 8 + slot;
        const size_t aoff = (size_t)item * (NNODE * NNODE);

        for (int k = lane; k < NNODE * NNODE; k += 32) {
            int n = k / NNODE;
            int m = k - n * NNODE;
            float v = adj[aoff + k];
            if (n == m) v += 1.0f;
            sm.Ah[n][m] = v;
        }
        float xs = 0.f;
        if (lane < NNODE) xs = x_str[(size_t)item * NNODE + lane];
        if (lane < NNODE) {
            float d = 0.f;
            #pragma unroll
            for (int m = 0; m < NNODE; ++m) d += sm.Ah[lane][m];
            float di = (d > 0.f) ? rsqrtf(d) : 0.f;
            sm.dinv[lane] = di;
            sm.xd[lane]   = di * xs;
        }
        if (lane < NNODE) {
            float a = 0.f;
            #pragma unroll
            for (int m = 0; m < NNODE; ++m) a += sm.Ah[lane][m] * sm.xd[m];
            sm.ex[lane] = a * sm.dinv[lane];
        }
        float h1d[NNODE];
        #pragma unroll
        for (int m = 0; m < NNODE; ++m) {
            float a = sm.ex[m] * W1o + b1o;
            float h = (a > 0.f) ? a : (__expf(a) - 1.0f);
            h1d[m] = sm.dinv[m] * h;
        }

        float emb = 0.f;
        for (int n = 0; n < NNODE; ++n) {
            const float4* rowv = reinterpret_cast<const float4*>(sm.Ah[n]);
            float4 r0 = rowv[0], r1 = rowv[1], r2 = rowv[2], r3 = rowv[3];
            float acc;
            acc  = r0.x*h1d[0]  + r0.y*h1d[1]  + r0.z*h1d[2]  + r0.w*h1d[3];
            acc += r1.x*h1d[4]  + r1.y*h1d[5]  + r1.z*h1d[6]  + r1.w*h1d[7];
            acc += r2.x*h1d[8]  + r2.y*h1d[9]  + r2.z*h1d[10] + r2.w*h1d[11];
            acc += r3.x*h1d[12] + r3.y*h1d[13] + r3.z*h1d[14] + r3.w*h1d[15];
            acc += sm.Ah[n][16] * h1d[16];
            float a2 = acc * sm.dinv[n];
            sm.ex[lane] = a2;
            const float4* exv = reinterpret_cast<const float4*>(sm.ex);
            float hacc = b2o;
            #pragma unroll
            for (int q = 0; q < 8; ++q) {
                float4 e = exv[q];
                hacc += e.x * W2col[4*q]   + e.y * W2col[4*q+1]
                      + e.z * W2col[4*q+2] + e.w * W2col[4*q+3];
            }
            float h2 = (hacc > 0.f) ? hacc : (__expf(hacc) - 1.0f);
            if constexpr (PASS == 1) {
                psum[n] += h2;
                psq[n]  += h2 * h2;
            } else {
                emb += s17[n] * h2;
            }
        }

        if constexpr (PASS == 2) {
            emb += s17[NNODE];
            sm.c[lane] = emb;
            if (lane < NNODE) sm.c[HH + lane] = x_raw[(size_t)item * NNODE + lane];
            if (lane < 3)     sm.c[49 + lane] = x_cov[(size_t)item * 3 + lane];
            if (lane == 0)    sm.c[52] = age[item];
            float a1 = hw[3392 + lane];
            float a2h = hw[3392 + 32 + lane];
            for (int i = 0; i < 52; i += 4) {
                float4 cv = *reinterpret_cast<const float4*>(&sm.c[i]);
                #pragma unroll
                for (int u = 0; u < 4; ++u) {
                    float cu = (&cv.x)[u];
                    float2 w2 = *reinterpret_cast<const float2*>(&hw[(i + u) * 64 + lane * 2]);
                    a1  += cu * w2.x;
                    a2h += cu * w2.y;
                }
            }
            {
                float cu = sm.c[52];
                float2 w2 = *reinterpret_cast<const float2*>(&hw[52 * 64 + lane * 2]);
                a1 += cu * w2.x; a2h += cu * w2.y;
            }
            a1 = fmaxf(a1, 0.f); a2h = fmaxf(a2h, 0.f);
            sm.z[lane] = a1;
            sm.z[32 + lane] = a2h;
            float acc = br2o;
            for (int i = 0; i < 64; i += 4) {
                float4 zv = *reinterpret_cast<const float4*>(&sm.z[i]);
                #pragma unroll
                for (int u = 0; u < 4; ++u)
                    acc += (&zv.x)[u] * hw[3456 + (i + u) * 32 + lane];
            }
            acc = fmaxf(acc, 0.f);
            float v = acc * Wr3o;
            v += __shfl_xor(v, 16, 32);
            v += __shfl_xor(v, 8, 32);
            v += __shfl_xor(v, 4, 32);
            v += __shfl_xor(v, 2, 32);
            v += __shfl_xor(v, 1, 32);
            if (lane == 0) {
                float s = v + br3v;
                out[item] = 1.0f / (1.0f + __expf(-s));
            }
        }
    }

    if constexpr (PASS == 1) {
        #pragma unroll
        for (int n = 0; n < NNODE; ++n) {
            float a = psum[n], b = psq[n];
            #pragma unroll
            for (int m = 32; m >= 1; m >>= 1) {
                a += __shfl_xor(a, m, 64);
                b += __shfl_xor(b, m, 64);
            }
            psum[n] = a; psq[n] = b;
        }
        const int wv = tid >> 6;
        if ((tid & 63) == 0) {
            #pragma unroll
            for (int n = 0; n < NNODE; ++n) {
                statb[wv * 34 + n]         = psum[n];
                statb[wv * 34 + NNODE + n] = psq[n];
            }
        }
        __syncthreads();
        if (tid < 34) {
            float s = statb[tid] + statb[34 + tid] + statb[68 + tid] + statb[102 + tid];
            unsafeAtomicAdd(&gstat[tid], s);
        }
    }
}

extern "C" void kernel_launch(void* const* d_in, const int* in_sizes, int n_in,
                              void* d_out, int out_size, void* d_ws, size_t ws_size,
                              hipStream_t stream) {
    (void)in_sizes; (void)n_in; (void)out_size;
    const float* x_str = (const float*)d_in[0];
    const float* x_raw = (const float*)d_in[1];
    const float* adj   = (const float*)d_in[2];
    const float* x_cov = (const float*)d_in[3];
    const float* age   = (const float*)d_in[4];
    const float* W1    = (const float*)d_in[5];
    const float* b1    = (const float*)d_in[6];
    const float* W2    = (const float*)d_in[7];
    const float* b2    = (const float*)d_in[8];
    const float* gamma = (const float*)d_in[9];
    const float* beta  = (const float*)d_in[10];
    const float* Wr1   = (const float*)d_in[11];
    const float* br1   = (const float*)d_in[12];
    const float* Wr2   = (const float*)d_in[13];
    const float* br2   = (const float*)d_in[14];
    const float* Wr3   = (const float*)d_in[15];
    const float* br3   = (const float*)d_in[16];
    float* gstat = (float*)d_ws;
    float* out   = (float*)d_out;

    const size_t need = 256 + (size_t)BTOT * 544 * 2;
    hipMemsetAsync(d_ws, 0, 34 * sizeof(float), stream);
    if (ws_size >= need) {
        __hip_bfloat16* h2g = (__hip_bfloat16*)((char*)d_ws + 256);
        pass1_kernel<<<2048, 256, 0, stream>>>(x_str, adj, W1, b1, W2, b2, h2g, gstat);
        pass2_kernel<<<2048, 256, 0, stream>>>(h2g, x_raw, x_cov, age, gamma, beta,
            Wr1, br1, Wr2, br2, Wr3, br3, gstat, out);
    } else {
        gcn_fb_kernel<1><<<2048, 256, 0, stream>>>(x_str, x_raw, adj, x_cov, age,
            W1, b1, W2, b2, gamma, beta, Wr1, br1, Wr2, br2, Wr3, br3, gstat, out);
        gcn_fb_kernel<2><<<2048, 256, 0, stream>>>(x_str, x_raw, adj, x_cov, age,
            W1, b1, W2, b2, gamma, beta, Wr1, br1, Wr2, br2, Wr3, br3, gstat, out);
    }
}

// Round 15
// 149.470 us; speedup vs baseline: 1.0387x; 1.0387x over previous
//
#include <hip/hip_runtime.h>
#include <hip/hip_bf16.h>
#include <math.h>

#define NNODE   17
#define HH      32
#define BTOT    131072
#define AHSTR   20      // floats per Ah row (80 B: 16B-aligned)
#define H1STR   40      // shorts per h1dT/g row (80 B; 2-way bank aliasing = free)
#define ZSTR    20      // shorts per zl out1-row (40 B; 8B-aligned uint2 packs)

typedef __attribute__((ext_vector_type(8))) short short8v;
typedef __attribute__((ext_vector_type(4))) float f32x4;

__device__ __forceinline__ float elu(float a) {
    return (a > 0.f) ? a : (__expf(a) - 1.0f);
}
__device__ __forceinline__ short bf16s(float x) {
    __hip_bfloat16 h = __float2bfloat16(x);
    return *reinterpret_cast<short*>(&h);
}
__device__ __forceinline__ float bfround(float x) {
    return __bfloat162float(__float2bfloat16(x));
}
__device__ __forceinline__ float blo(unsigned u){ return __uint_as_float(u << 16); }
__device__ __forceinline__ float bhi(unsigned u){ return __uint_as_float(u & 0xFFFF0000u); }
__device__ __forceinline__ unsigned pack2(float a, float b) {
    return ((unsigned)(unsigned short)bf16s(a)) | (((unsigned)(unsigned short)bf16s(b)) << 16);
}
// nontemporal (evict-first) load: keep one-shot streams (adj) out of L3 so h2g stays resident
__device__ __forceinline__ float ntload(const float* p) {
    return __builtin_nontemporal_load(p);
}
// nontemporal store: stream h2g past L2 so no dirty-L2 drain gates pass2's reads
__device__ __forceinline__ void ntstore16(short* p, short v) {
    __builtin_nontemporal_store(v, p);
}

// ---------------------------------------------------------------- PASS 1 (R12 structure + NT h2g stores)
struct __align__(16) SlotB {
    float Ah[NNODE * AHSTR];
    float dinv[20];
    float xd[20];
    float ag[20];
    __hip_bfloat16 h1dT[32 * H1STR];
    __hip_bfloat16 g[NNODE * H1STR + 8];
};

__global__ __launch_bounds__(256) void pass1_kernel(
    const float* __restrict__ x_str, const float* __restrict__ adj,
    const float* __restrict__ W1, const float* __restrict__ b1,
    const float* __restrict__ W2, const float* __restrict__ b2,
    __hip_bfloat16* __restrict__ h2g, float* __restrict__ gstat)
{
    __shared__ SlotB sa[8];
    __shared__ float statb[4 * 34];

    const int tid  = threadIdx.x;
    const int slot = tid >> 5;
    const int lane = tid & 31;
    const int l64  = tid & 63;
    const int w    = tid >> 6;
    SlotB& sm = sa[slot];
    short* hs = reinterpret_cast<short*>(h2g);

    const float W1o = W1[lane], b1o = b1[lane];

    const int col = l64 & 15;
    const int grp = l64 >> 4;
    short8v wh0, wl0, wh1, wl1;
    #pragma unroll
    for (int j = 0; j < 8; ++j) {
        float w0 = W2[(8 * grp + j) * 32 + col];
        float w1 = W2[(8 * grp + j) * 32 + col + 16];
        wh0[j] = bf16s(w0); wl0[j] = bf16s(w0 - bfround(w0));
        wh1[j] = bf16s(w1); wl1[j] = bf16s(w1 - bfround(w1));
    }
    const float b2c0 = b2[col];
    const float b2c1 = b2[col + 16];

    float s4[4] = {0.f, 0.f, 0.f, 0.f};
    float q4[4] = {0.f, 0.f, 0.f, 0.f};
    float s16 = 0.f, q16 = 0.f;

    for (int z = lane; z < NNODE * AHSTR; z += 32) sm.Ah[z] = 0.f;
    {
        unsigned* hz = reinterpret_cast<unsigned*>(sm.h1dT);
        for (int z = lane; z < 16 * H1STR; z += 32) hz[z] = 0u;
    }

    const int base = blockIdx.x * 64;

    float rbuf[10];
    float rxs;
    {
        const size_t aoff0 = (size_t)(base + slot) * (NNODE * NNODE);
        #pragma unroll
        for (int j = 0; j < 9; ++j) rbuf[j] = ntload(&adj[aoff0 + j * 32 + lane]);
        rbuf[9] = (lane == 0) ? ntload(&adj[aoff0 + 288]) : 0.f;
        rxs = (lane < NNODE) ? ntload(&x_str[(size_t)(base + slot) * NNODE + lane]) : 0.f;
    }

    for (int it = 0; it < 8; ++it) {
        const int item = base + it * 8 + slot;

        #pragma unroll
        for (int j = 0; j < 10; ++j) {
            const int k2 = j * 32 + lane;
            if (j < 9 || lane == 0) {
                int n = (k2 * 241) >> 12;
                int m = k2 - n * NNODE;
                sm.Ah[n * AHSTR + m] = (n == m) ? rbuf[j] + 1.0f : rbuf[j];
            }
        }
        const float xs = rxs;

        if (it < 7) {
            const size_t aoffn = (size_t)(item + 8) * (NNODE * NNODE);
            #pragma unroll
            for (int j = 0; j < 9; ++j) rbuf[j] = ntload(&adj[aoffn + j * 32 + lane]);
            rbuf[9] = (lane == 0) ? ntload(&adj[aoffn + 288]) : 0.f;
            rxs = (lane < NNODE) ? ntload(&x_str[(size_t)(item + 8) * NNODE + lane]) : 0.f;
        }

        float row[NNODE];
        float di = 0.f;
        if (lane < NNODE) {
            const float4* rp = reinterpret_cast<const float4*>(&sm.Ah[lane * AHSTR]);
            float4 a0 = rp[0], a1 = rp[1], a2 = rp[2], a3 = rp[3];
            row[0]=a0.x; row[1]=a0.y; row[2]=a0.z; row[3]=a0.w;
            row[4]=a1.x; row[5]=a1.y; row[6]=a1.z; row[7]=a1.w;
            row[8]=a2.x; row[9]=a2.y; row[10]=a2.z; row[11]=a2.w;
            row[12]=a3.x; row[13]=a3.y; row[14]=a3.z; row[15]=a3.w;
            row[16] = sm.Ah[lane * AHSTR + 16];
            float d = 0.f;
            #pragma unroll
            for (int m = 0; m < NNODE; ++m) d += row[m];
            di = (d > 0.f) ? rsqrtf(d) : 0.f;
            sm.dinv[lane] = di;
            sm.xd[lane]   = di * xs;
        }
        if (lane < NNODE) {
            const float4* xp = reinterpret_cast<const float4*>(sm.xd);
            float4 x0 = xp[0], x1 = xp[1], x2 = xp[2], x3 = xp[3];
            float a;
            a  = row[0]*x0.x + row[1]*x0.y + row[2]*x0.z + row[3]*x0.w;
            a += row[4]*x1.x + row[5]*x1.y + row[6]*x1.z + row[7]*x1.w;
            a += row[8]*x2.x + row[9]*x2.y + row[10]*x2.z + row[11]*x2.w;
            a += row[12]*x3.x + row[13]*x3.y + row[14]*x3.z + row[15]*x3.w;
            a += row[16] * sm.xd[16];
            sm.ag[lane] = a * di;
        }
        float h1d[NNODE];
        {
            const float4* dp = reinterpret_cast<const float4*>(sm.dinv);
            const float4* ap = reinterpret_cast<const float4*>(sm.ag);
            float dv[NNODE], av[NNODE];
            #pragma unroll
            for (int q = 0; q < 4; ++q) {
                float4 d4 = dp[q], a4 = ap[q];
                dv[4*q]=d4.x; dv[4*q+1]=d4.y; dv[4*q+2]=d4.z; dv[4*q+3]=d4.w;
                av[4*q]=a4.x; av[4*q+1]=a4.y; av[4*q+2]=a4.z; av[4*q+3]=a4.w;
            }
            dv[16] = sm.dinv[16]; av[16] = sm.ag[16];
            #pragma unroll
            for (int m = 0; m < NNODE; ++m) {
                float a = av[m] * W1o + b1o;
                h1d[m] = dv[m] * elu(a);
            }
        }
        {
            uint2* hw2 = reinterpret_cast<uint2*>(&sm.h1dT[lane * H1STR]);
            #pragma unroll
            for (int p = 0; p < 4; ++p) {
                uint2 v;
                v.x = pack2(h1d[4 * p],     h1d[4 * p + 1]);
                v.y = pack2(h1d[4 * p + 2], h1d[4 * p + 3]);
                hw2[p] = v;
            }
            reinterpret_cast<short*>(sm.h1dT)[lane * H1STR + 16] = bf16s(h1d[16]);
        }
        {
            const float4* rp16 = reinterpret_cast<const float4*>(&sm.Ah[16 * AHSTR]);
            float4 b0 = rp16[0], b1v = rp16[1], b2v = rp16[2], b3 = rp16[3];
            float a16;
            a16  = b0.x*h1d[0]  + b0.y*h1d[1]  + b0.z*h1d[2]  + b0.w*h1d[3];
            a16 += b1v.x*h1d[4] + b1v.y*h1d[5] + b1v.z*h1d[6] + b1v.w*h1d[7];
            a16 += b2v.x*h1d[8] + b2v.y*h1d[9] + b2v.z*h1d[10]+ b2v.w*h1d[11];
            a16 += b3.x*h1d[12] + b3.y*h1d[13] + b3.z*h1d[14] + b3.w*h1d[15];
            a16 += sm.Ah[16 * AHSTR + 16] * h1d[16];
            reinterpret_cast<short*>(sm.g)[16 * H1STR + lane] =
                bf16s(a16 * sm.dinv[16]);
        }

        #pragma unroll
        for (int i = 0; i < 2; ++i) {
            SlotB& si = sa[2 * w + i];
            const float dn = si.dinv[col];
            short8v ah;
            if (grp < 3) {
                float4 f0 = *reinterpret_cast<const float4*>(&si.Ah[col * AHSTR + grp * 8]);
                float4 f1 = *reinterpret_cast<const float4*>(&si.Ah[col * AHSTR + grp * 8 + 4]);
                float vv[8] = {f0.x, f0.y, f0.z, f0.w, f1.x, f1.y, f1.z, f1.w};
                #pragma unroll
                for (int j = 0; j < 8; ++j) ah[j] = bf16s(dn * vv[j]);
            } else {
                #pragma unroll
                for (int j = 0; j < 8; ++j) ah[j] = 0;
            }
            #pragma unroll
            for (int h = 0; h < 2; ++h) {
                short8v bq = *reinterpret_cast<const short8v*>(
                    &si.h1dT[(col + 16 * h) * H1STR + grp * 8]);
                f32x4 c = {0.f, 0.f, 0.f, 0.f};
                c = __builtin_amdgcn_mfma_f32_16x16x32_bf16(ah, bq, c, 0, 0, 0);
                #pragma unroll
                for (int r = 0; r < 4; ++r) {
                    reinterpret_cast<short*>(si.g)[(grp * 4 + r) * H1STR + col + 16 * h] =
                        bf16s(c[r]);
                }
            }
        }

        // ==== phase B: h2 = elu(agg2 @ W2 + b2); NT stores stream past L2
        #pragma unroll
        for (int i = 0; i < 2; ++i) {
            const int itm = base + it * 8 + 2 * w + i;
            short8v a = *reinterpret_cast<const short8v*>(
                &sa[2 * w + i].g[col * H1STR + grp * 8]);
            f32x4 c0 = {b2c0, b2c0, b2c0, b2c0};
            f32x4 c1 = {b2c1, b2c1, b2c1, b2c1};
            c0 = __builtin_amdgcn_mfma_f32_16x16x32_bf16(a, wh0, c0, 0, 0, 0);
            c0 = __builtin_amdgcn_mfma_f32_16x16x32_bf16(a, wl0, c0, 0, 0, 0);
            c1 = __builtin_amdgcn_mfma_f32_16x16x32_bf16(a, wh1, c1, 0, 0, 0);
            c1 = __builtin_amdgcn_mfma_f32_16x16x32_bf16(a, wl1, c1, 0, 0, 0);
            #pragma unroll
            for (int r = 0; r < 4; ++r) {
                float h0 = elu(c0[r]);
                float h1 = elu(c1[r]);
                const size_t ob = (size_t)itm * 544 + (grp * 4 + r) * 32 + col;
                ntstore16(hs + ob,      bf16s(h0));
                ntstore16(hs + ob + 16, bf16s(h1));
                s4[r] += h0 + h1;
                q4[r] += h0 * h0 + h1 * h1;
            }
        }
        {
            const int ii = (l64 & 15) & 1;
            short8v a = *reinterpret_cast<const short8v*>(
                &sa[2 * w + ii].g[16 * H1STR + grp * 8]);
            f32x4 c0 = {b2c0, b2c0, b2c0, b2c0};
            f32x4 c1 = {b2c1, b2c1, b2c1, b2c1};
            c0 = __builtin_amdgcn_mfma_f32_16x16x32_bf16(a, wh0, c0, 0, 0, 0);
            c0 = __builtin_amdgcn_mfma_f32_16x16x32_bf16(a, wl0, c0, 0, 0, 0);
            c1 = __builtin_amdgcn_mfma_f32_16x16x32_bf16(a, wh1, c1, 0, 0, 0);
            c1 = __builtin_amdgcn_mfma_f32_16x16x32_bf16(a, wl1, c1, 0, 0, 0);
            if (grp == 0) {
                #pragma unroll
                for (int r = 0; r < 2; ++r) {
                    float h0 = elu(c0[r]);
                    float h1 = elu(c1[r]);
                    const size_t ob =
                        (size_t)(base + it * 8 + 2 * w + r) * 544 + 16 * 32 + col;
                    ntstore16(hs + ob,      bf16s(h0));
                    ntstore16(hs + ob + 16, bf16s(h1));
                    s16 += h0 + h1;
                    q16 += h0 * h0 + h1 * h1;
                }
            }
        }
    }

    #pragma unroll
    for (int m = 1; m <= 8; m <<= 1) {
        #pragma unroll
        for (int r = 0; r < 4; ++r) {
            s4[r] += __shfl_xor(s4[r], m, 64);
            q4[r] += __shfl_xor(q4[r], m, 64);
        }
        s16 += __shfl_xor(s16, m, 64);
        q16 += __shfl_xor(q16, m, 64);
    }
    if ((l64 & 15) == 0) {
        #pragma unroll
        for (int r = 0; r < 4; ++r) {
            const int n = grp * 4 + r;
            statb[w * 34 + n]         = s4[r];
            statb[w * 34 + NNODE + n] = q4[r];
        }
        if (grp == 0) {
            statb[w * 34 + 16]         = s16;
            statb[w * 34 + NNODE + 16] = q16;
        }
    }
    __syncthreads();
    if (tid < 34) {
        float s = statb[tid] + statb[34 + tid] + statb[68 + tid] + statb[102 + tid];
        unsafeAtomicAdd(&gstat[tid], s);
    }
}

// ---------------------------------------------------------------- PASS 2 (R12 head, unchanged)
__global__ __launch_bounds__(256) void pass2_kernel(
    const __hip_bfloat16* __restrict__ h2g,
    const float* __restrict__ x_raw, const float* __restrict__ x_cov,
    const float* __restrict__ age,
    const float* __restrict__ gamma, const float* __restrict__ beta,
    const float* __restrict__ Wr1, const float* __restrict__ br1,
    const float* __restrict__ Wr2, const float* __restrict__ br2,
    const float* __restrict__ Wr3, const float* __restrict__ br3,
    const float* __restrict__ gstat, float* __restrict__ out)
{
    __shared__ short8v wf1[8][64];
    __shared__ short8v wf2[8][64];
    __shared__ __hip_bfloat16 zl[4][64 * ZSTR];
    __shared__ float   s17[18];

    const int tid = threadIdx.x;
    const int w   = tid >> 6;
    const int l   = tid & 63;
    const int col = l & 15;
    const int g   = l >> 4;
    const int ibase = blockIdx.x * 64;
    const int wb    = ibase + w * 16;
    const int item  = wb + col;

    if (tid == 0) {
        const float invBH = 1.0f / ((float)BTOT * (float)HH);
        float Cs = 0.f;
        #pragma unroll
        for (int n = 0; n < NNODE; ++n) {
            float mean = gstat[n] * invBH;
            float var  = gstat[NNODE + n] * invBH - mean * mean;
            float sc   = gamma[n] * rsqrtf(var + 1e-5f);
            s17[n] = sc * (1.0f / (float)NNODE);
            Cs += beta[n] - mean * sc;
        }
        s17[NNODE] = Cs * (1.0f / (float)NNODE);
    }

    for (int idx = tid; idx < 8 * 64; idx += 256) {
        int fid = idx >> 6, tl = idx & 63;
        int kst = fid >> 2, nt = fid & 3;
        int tc = tl & 15, tg = tl >> 4;
        short8v v;
        #pragma unroll
        for (int j = 0; j < 8; ++j) {
            int k = kst * 32 + tg * 8 + j;
            float f = (k < 53) ? Wr1[k * 64 + nt * 16 + tc] : 0.f;
            v[j] = bf16s(f);
        }
        wf1[fid][tl] = v;
    }
    for (int idx = tid; idx < 8 * 64; idx += 256) {
        int fid = idx >> 6, tl = idx & 63;
        int kst = fid >> 2, mt = (fid >> 1) & 1, hl = fid & 1;
        int tc = tl & 15, tg = tl >> 4;
        short8v v;
        #pragma unroll
        for (int j = 0; j < 8; ++j) {
            int k = kst * 32 + tg * 8 + j;
            float f = Wr2[k * 32 + mt * 16 + tc];
            v[j] = hl ? bf16s(f - bfround(f)) : bf16s(f);
        }
        wf2[fid][tl] = v;
    }
    __syncthreads();

    float emb[8];
    const float cst = s17[NNODE];
    #pragma unroll
    for (int j = 0; j < 8; ++j) emb[j] = cst;
    const __hip_bfloat16* hp = h2g + (size_t)item * 544 + g * 8;
    #pragma unroll
    for (int n = 0; n < NNODE; ++n) {
        uint4 v = *reinterpret_cast<const uint4*>(hp + n * 32);
        float sn = s17[n];
        emb[0] += sn * blo(v.x); emb[1] += sn * bhi(v.x);
        emb[2] += sn * blo(v.y); emb[3] += sn * bhi(v.y);
        emb[4] += sn * blo(v.z); emb[5] += sn * bhi(v.z);
        emb[6] += sn * blo(v.w); emb[7] += sn * bhi(v.w);
    }

    float tail[8];
    if (g < 2) {
        const float* xr = x_raw + (size_t)item * 17 + g * 8;
        #pragma unroll
        for (int j = 0; j < 8; ++j) tail[j] = xr[j];
    } else if (g == 2) {
        tail[0] = x_raw[(size_t)item * 17 + 16];
        tail[1] = x_cov[(size_t)item * 3 + 0];
        tail[2] = x_cov[(size_t)item * 3 + 1];
        tail[3] = x_cov[(size_t)item * 3 + 2];
        tail[4] = age[item];
        tail[5] = 0.f; tail[6] = 0.f; tail[7] = 0.f;
    } else {
        #pragma unroll
        for (int j = 0; j < 8; ++j) tail[j] = 0.f;
    }

    short8v a0h, a0l, a1h, a1l;
    #pragma unroll
    for (int j = 0; j < 8; ++j) {
        float f = emb[j];
        a0h[j] = bf16s(f); a0l[j] = bf16s(f - bfround(f));
        float f1 = tail[j];
        a1h[j] = bf16s(f1); a1l[j] = bf16s(f1 - bfround(f1));
    }

    f32x4 C1[4];
    #pragma unroll
    for (int nt = 0; nt < 4; ++nt) {
        float b = br1[nt * 16 + col];
        C1[nt] = (f32x4){b, b, b, b};
        C1[nt] = __builtin_amdgcn_mfma_f32_16x16x32_bf16(a0h, wf1[nt    ][l], C1[nt], 0, 0, 0);
        C1[nt] = __builtin_amdgcn_mfma_f32_16x16x32_bf16(a0l, wf1[nt    ][l], C1[nt], 0, 0, 0);
        C1[nt] = __builtin_amdgcn_mfma_f32_16x16x32_bf16(a1h, wf1[4 + nt][l], C1[nt], 0, 0, 0);
        C1[nt] = __builtin_amdgcn_mfma_f32_16x16x32_bf16(a1l, wf1[4 + nt][l], C1[nt], 0, 0, 0);
    }
    #pragma unroll
    for (int nt = 0; nt < 4; ++nt) {
        uint2 v;
        v.x = pack2(fmaxf(C1[nt][0], 0.f), fmaxf(C1[nt][1], 0.f));
        v.y = pack2(fmaxf(C1[nt][2], 0.f), fmaxf(C1[nt][3], 0.f));
        *reinterpret_cast<uint2*>(&zl[w][(nt * 16 + col) * ZSTR + g * 4]) = v;
    }

    f32x4 C2[2];
    #pragma unroll
    for (int mt = 0; mt < 2; ++mt)
        C2[mt] = (f32x4){br2[mt*16 + g*4], br2[mt*16 + g*4 + 1],
                         br2[mt*16 + g*4 + 2], br2[mt*16 + g*4 + 3]};
    #pragma unroll
    for (int kst = 0; kst < 2; ++kst) {
        short8v bh;
        #pragma unroll
        for (int j = 0; j < 8; ++j)
            bh[j] = reinterpret_cast<const short*>(zl[w])[(kst * 32 + g * 8 + j) * ZSTR + col];
        #pragma unroll
        for (int mt = 0; mt < 2; ++mt) {
            C2[mt] = __builtin_amdgcn_mfma_f32_16x16x32_bf16(wf2[kst*4 + mt*2    ][l], bh, C2[mt], 0, 0, 0);
            C2[mt] = __builtin_amdgcn_mfma_f32_16x16x32_bf16(wf2[kst*4 + mt*2 + 1][l], bh, C2[mt], 0, 0, 0);
        }
    }

    float sum = 0.f;
    #pragma unroll
    for (int mt = 0; mt < 2; ++mt)
        #pragma unroll
        for (int r = 0; r < 4; ++r)
            sum += fmaxf(C2[mt][r], 0.f) * Wr3[mt * 16 + g * 4 + r];
    sum += __shfl_xor(sum, 16, 64);
    sum += __shfl_xor(sum, 32, 64);
    if (l < 16)
        out[wb + l] = 1.0f / (1.0f + __expf(-(sum + br3[0])));
}

// ---------------------------------------------------------------- fallback (round-0, passing)
struct __align__(16) SlotMem {
    float Ah[NNODE][20];
    float dinv[20];
    float xd[20];
    float ex[32];
    float c[56];
    float z[64];
};

template<int PASS>
__global__ __launch_bounds__(256) void gcn_fb_kernel(
    const float* __restrict__ x_str, const float* __restrict__ x_raw,
    const float* __restrict__ adj,   const float* __restrict__ x_cov,
    const float* __restrict__ age,
    const float* __restrict__ W1, const float* __restrict__ b1,
    const float* __restrict__ W2, const float* __restrict__ b2,
    const float* __restrict__ gamma, const float* __restrict__ beta,
    const float* __restrict__ Wr1, const float* __restrict__ br1,
    const float* __restrict__ Wr2, const float* __restrict__ br2,
    const float* __restrict__ Wr3, const float* __restrict__ br3,
    float* __restrict__ gstat, float* __restrict__ out)
{
    __shared__ SlotMem slots[8];
    __shared__ __align__(16) float hw[(PASS == 2) ? 5504 : 1];
    __shared__ float s17[(PASS == 2) ? 18 : 1];
    __shared__ float statb[(PASS == 1) ? 4 * 34 : 1];

    const int tid  = threadIdx.x;
    const int slot = tid >> 5;
    const int lane = tid & 31;
    SlotMem& sm = slots[slot];

    const float W1o = W1[lane];
    const float b1o = b1[lane];
    const float b2o = b2[lane];
    float W2col[HH];
    #pragma unroll
    for (int k = 0; k < HH; ++k) W2col[k] = W2[k * HH + lane];

    float Wr3o = 0.f, br2o = 0.f, br3v = 0.f;
    if constexpr (PASS == 2) {
        Wr3o = Wr3[lane];
        br2o = br2[lane];
        br3v = br3[0];
        for (int t = tid; t < 5504; t += 256) {
            float v;
            if (t < 3392) {
                int i = t >> 6, r = t & 63;
                v = Wr1[i * 64 + ((r & 1) << 5) + (r >> 1)];
            } else if (t < 3456) {
                v = br1[t - 3392];
            } else {
                v = Wr2[t - 3456];
            }
            hw[t] = v;
        }
        if (tid == 0) {
            const float invBH = 1.0f / ((float)BTOT * (float)HH);
            float Cs = 0.f;
            #pragma unroll
            for (int n = 0; n < NNODE; ++n) {
                float mean = gstat[n] * invBH;
                float var  = gstat[NNODE + n] * invBH - mean * mean;
                float sc   = gamma[n] * rsqrtf(var + 1e-5f);
                s17[n] = sc * (1.0f / (float)NNODE);
                Cs += beta[n] - mean * sc;
            }
            s17[NNODE] = Cs * (1.0f / (float)NNODE);
        }
        __syncthreads();
    }

    float psum[NNODE], psq[NNODE];
    if constexpr (PASS == 1) {
        #pragma unroll
        for (int n = 0; n < NNODE; ++n) { psum[n] = 0.f; psq[n] = 0.f; }
    }

    const int base = blockIdx.x * 64;
    for (int it = 0; it < 8; ++it) {
        const int item = base + it * 8 + slot;
        const size_t aoff = (size_t)item * (NNODE * NNODE);

        for (int k = lane; k < NNODE * NNODE; k += 32) {
            int n = k / NNODE;
            int m = k - n * NNODE;
            float v = adj[aoff + k];
            if (n == m) v += 1.0f;
            sm.Ah[n][m] = v;
        }
        float xs = 0.f;
        if (lane < NNODE) xs = x_str[(size_t)item * NNODE + lane];
        if (lane < NNODE) {
            float d = 0.f;
            #pragma unroll
            for (int m = 0; m < NNODE; ++m) d += sm.Ah[lane][m];
            float di = (d > 0.f) ? rsqrtf(d) : 0.f;
            sm.dinv[lane] = di;
            sm.xd[lane]   = di * xs;
        }
        if (lane < NNODE) {
            float a = 0.f;
            #pragma unroll
            for (int m = 0; m < NNODE; ++m) a += sm.Ah[lane][m] * sm.xd[m];
            sm.ex[lane] = a * sm.dinv[lane];
        }
        float h1d[NNODE];
        #pragma unroll
        for (int m = 0; m < NNODE; ++m) {
            float a = sm.ex[m] * W1o + b1o;
            float h = (a > 0.f) ? a : (__expf(a) - 1.0f);
            h1d[m] = sm.dinv[m] * h;
        }

        float emb = 0.f;
        for (int n = 0; n < NNODE; ++n) {
            const float4* rowv = reinterpret_cast<const float4*>(sm.Ah[n]);
            float4 r0 = rowv[0], r1 = rowv[1], r2 = rowv[2], r3 = rowv[3];
            float acc;
            acc  = r0.x*h1d[0]  + r0.y*h1d[1]  + r0.z*h1d[2]  + r0.w*h1d[3];
            acc += r1.x*h1d[4]  + r1.y*h1d[5]  + r1.z*h1d[6]  + r1.w*h1d[7];
            acc += r2.x*h1d[8]  + r2.y*h1d[9]  + r2.z*h1d[10] + r2.w*h1d[11];
            acc += r3.x*h1d[12] + r3.y*h1d[13] + r3.z*h1d[14] + r3.w*h1d[15];
            acc += sm.Ah[n][16] * h1d[16];
            float a2 = acc * sm.dinv[n];
            sm.ex[lane] = a2;
            const float4* exv = reinterpret_cast<const float4*>(sm.ex);
            float hacc = b2o;
            #pragma unroll
            for (int q = 0; q < 8; ++q) {
                float4 e = exv[q];
                hacc += e.x * W2col[4*q]   + e.y * W2col[4*q+1]
                      + e.z * W2col[4*q+2] + e.w * W2col[4*q+3];
            }
            float h2 = (hacc > 0.f) ? hacc : (__expf(hacc) - 1.0f);
            if constexpr (PASS == 1) {
                psum[n] += h2;
                psq[n]  += h2 * h2;
            } else {
                emb += s17[n] * h2;
            }
        }

        if constexpr (PASS == 2) {
            emb += s17[NNODE];
            sm.c[lane] = emb;
            if (lane < NNODE) sm.c[HH + lane] = x_raw[(size_t)item * NNODE + lane];
            if (lane < 3)     sm.c[49 + lane] = x_cov[(size_t)item * 3 + lane];
            if (lane == 0)    sm.c[52] = age[item];
            float a1 = hw[3392 + lane];
            float a2h = hw[3392 + 32 + lane];
            for (int i = 0; i < 52; i += 4) {
                float4 cv = *reinterpret_cast<const float4*>(&sm.c[i]);
                #pragma unroll
                for (int u = 0; u < 4; ++u) {
                    float cu = (&cv.x)[u];
                    float2 w2 = *reinterpret_cast<const float2*>(&hw[(i + u) * 64 + lane * 2]);
                    a1  += cu * w2.x;
                    a2h += cu * w2.y;
                }
            }
            {
                float cu = sm.c[52];
                float2 w2 = *reinterpret_cast<const float2*>(&hw[52 * 64 + lane * 2]);
                a1 += cu * w2.x; a2h += cu * w2.y;
            }
            a1 = fmaxf(a1, 0.f); a2h = fmaxf(a2h, 0.f);
            sm.z[lane] = a1;
            sm.z[32 + lane] = a2h;
            float acc = br2o;
            for (int i = 0; i < 64; i += 4) {
                float4 zv = *reinterpret_cast<const float4*>(&sm.z[i]);
                #pragma unroll
                for (int u = 0; u < 4; ++u)
                    acc += (&zv.x)[u] * hw[3456 + (i + u) * 32 + lane];
            }
            acc = fmaxf(acc, 0.f);
            float v = acc * Wr3o;
            v += __shfl_xor(v, 16, 32);
            v += __shfl_xor(v, 8, 32);
            v += __shfl_xor(v, 4, 32);
            v += __shfl_xor(v, 2, 32);
            v += __shfl_xor(v, 1, 32);
            if (lane == 0) {
                float s = v + br3v;
                out[item] = 1.0f / (1.0f + __expf(-s));
            }
        }
    }

    if constexpr (PASS == 1) {
        #pragma unroll
        for (int n = 0; n < NNODE; ++n) {
            float a = psum[n], b = psq[n];
            #pragma unroll
            for (int m = 32; m >= 1; m >>= 1) {
                a += __shfl_xor(a, m, 64);
                b += __shfl_xor(b, m, 64);
            }
            psum[n] = a; psq[n] = b;
        }
        const int wv = tid >> 6;
        if ((tid & 63) == 0) {
            #pragma unroll
            for (int n = 0; n < NNODE; ++n) {
                statb[wv * 34 + n]         = psum[n];
                statb[wv * 34 + NNODE + n] = psq[n];
            }
        }
        __syncthreads();
        if (tid < 34) {
            float s = statb[tid] + statb[34 + tid] + statb[68 + tid] + statb[102 + tid];
            unsafeAtomicAdd(&gstat[tid], s);
        }
    }
}

extern "C" void kernel_launch(void* const* d_in, const int* in_sizes, int n_in,
                              void* d_out, int out_size, void* d_ws, size_t ws_size,
                              hipStream_t stream) {
    (void)in_sizes; (void)n_in; (void)out_size;
    const float* x_str = (const float*)d_in[0];
    const float* x_raw = (const float*)d_in[1];
    const float* adj   = (const float*)d_in[2];
    const float* x_cov = (const float*)d_in[3];
    const float* age   = (const float*)d_in[4];
    const float* W1    = (const float*)d_in[5];
    const float* b1    = (const float*)d_in[6];
    const float* W2    = (const float*)d_in[7];
    const float* b2    = (const float*)d_in[8];
    const float* gamma = (const float*)d_in[9];
    const float* beta  = (const float*)d_in[10];
    const float* Wr1   = (const float*)d_in[11];
    const float* br1   = (const float*)d_in[12];
    const float* Wr2   = (const float*)d_in[13];
    const float* br2   = (const float*)d_in[14];
    const float* Wr3   = (const float*)d_in[15];
    const float* br3   = (const float*)d_in[16];
    float* gstat = (float*)d_ws;
    float* out   = (float*)d_out;

    const size_t need = 256 + (size_t)BTOT * 544 * 2;
    hipMemsetAsync(d_ws, 0, 34 * sizeof(float), stream);
    if (ws_size >= need) {
        __hip_bfloat16* h2g = (__hip_bfloat16*)((char*)d_ws + 256);
        pass1_kernel<<<2048, 256, 0, stream>>>(x_str, adj, W1, b1, W2, b2, h2g, gstat);
        pass2_kernel<<<2048, 256, 0, stream>>>(h2g, x_raw, x_cov, age, gamma, beta,
            Wr1, br1, Wr2, br2, Wr3, br3, gstat, out);
    } else {
        gcn_fb_kernel<1><<<2048, 256, 0, stream>>>(x_str, x_raw, adj, x_cov, age,
            W1, b1, W2, b2, gamma, beta, Wr1, br1, Wr2, br2, Wr3, br3, gstat, out);
        gcn_fb_kernel<2><<<2048, 256, 0, stream>>>(x_str, x_raw, adj, x_cov, age,
            W1, b1, W2, b2, gamma, beta, Wr1, br1, Wr2, br2, Wr3, br3, gstat, out);
    }
}

// Round 16
// 144.468 us; speedup vs baseline: 1.0746x; 1.0346x over previous
//
#include <hip/hip_runtime.h>
#include <hip/hip_bf16.h>
#include <math.h>

#define NNODE   17
#define HH      32
#define BTOT    131072
#define AHSTR   20      // floats per Ah row (80 B: 16B-aligned)
#define H1STR   40      // shorts per h1dT/g row (80 B; 2-way bank aliasing = free)
#define ZSTR    20      // shorts per zl out1-row (40 B; 8B-aligned uint2 packs)

typedef __attribute__((ext_vector_type(8))) short short8v;
typedef __attribute__((ext_vector_type(4))) float f32x4;

__device__ __forceinline__ float elu(float a) {
    return (a > 0.f) ? a : (__expf(a) - 1.0f);
}
__device__ __forceinline__ short bf16s(float x) {
    __hip_bfloat16 h = __float2bfloat16(x);
    return *reinterpret_cast<short*>(&h);
}
__device__ __forceinline__ float bfround(float x) {
    return __bfloat162float(__float2bfloat16(x));
}
__device__ __forceinline__ float blo(unsigned u){ return __uint_as_float(u << 16); }
__device__ __forceinline__ float bhi(unsigned u){ return __uint_as_float(u & 0xFFFF0000u); }
__device__ __forceinline__ unsigned pack2(float a, float b) {
    return ((unsigned)(unsigned short)bf16s(a)) | (((unsigned)(unsigned short)bf16s(b)) << 16);
}
// nontemporal (evict-first) load: keep one-shot streams (adj) out of L3 so h2g stays resident
__device__ __forceinline__ float ntload(const float* p) {
    return __builtin_nontemporal_load(p);
}

// ---------------------------------------------------------------- PASS 1 (R12: barrier-free GCN,
// intra-wave MFMA phases A+B, fused BN stats, adj register prefetch, NT adj loads)
struct __align__(16) SlotB {
    float Ah[NNODE * AHSTR];
    float dinv[20];
    float xd[20];
    float ag[20];
    __hip_bfloat16 h1dT[32 * H1STR];
    __hip_bfloat16 g[NNODE * H1STR + 8];
};

__global__ __launch_bounds__(256) void pass1_kernel(
    const float* __restrict__ x_str, const float* __restrict__ adj,
    const float* __restrict__ W1, const float* __restrict__ b1,
    const float* __restrict__ W2, const float* __restrict__ b2,
    __hip_bfloat16* __restrict__ h2g, float* __restrict__ gstat)
{
    __shared__ SlotB sa[8];
    __shared__ float statb[4 * 34];

    const int tid  = threadIdx.x;
    const int slot = tid >> 5;
    const int lane = tid & 31;
    const int l64  = tid & 63;
    const int w    = tid >> 6;
    SlotB& sm = sa[slot];

    const float W1o = W1[lane], b1o = b1[lane];

    const int col = l64 & 15;
    const int grp = l64 >> 4;
    short8v wh0, wl0, wh1, wl1;
    #pragma unroll
    for (int j = 0; j < 8; ++j) {
        float w0 = W2[(8 * grp + j) * 32 + col];
        float w1 = W2[(8 * grp + j) * 32 + col + 16];
        wh0[j] = bf16s(w0); wl0[j] = bf16s(w0 - bfround(w0));
        wh1[j] = bf16s(w1); wl1[j] = bf16s(w1 - bfround(w1));
    }
    const float b2c0 = b2[col];
    const float b2c1 = b2[col + 16];

    float s4[4] = {0.f, 0.f, 0.f, 0.f};
    float q4[4] = {0.f, 0.f, 0.f, 0.f};
    float s16 = 0.f, q16 = 0.f;

    for (int z = lane; z < NNODE * AHSTR; z += 32) sm.Ah[z] = 0.f;
    {
        unsigned* hz = reinterpret_cast<unsigned*>(sm.h1dT);
        for (int z = lane; z < 16 * H1STR; z += 32) hz[z] = 0u;
    }

    const int base = blockIdx.x * 64;

    float rbuf[10];
    float rxs;
    {
        const size_t aoff0 = (size_t)(base + slot) * (NNODE * NNODE);
        #pragma unroll
        for (int j = 0; j < 9; ++j) rbuf[j] = ntload(&adj[aoff0 + j * 32 + lane]);
        rbuf[9] = (lane == 0) ? ntload(&adj[aoff0 + 288]) : 0.f;
        rxs = (lane < NNODE) ? ntload(&x_str[(size_t)(base + slot) * NNODE + lane]) : 0.f;
    }

    for (int it = 0; it < 8; ++it) {
        const int item = base + it * 8 + slot;

        #pragma unroll
        for (int j = 0; j < 10; ++j) {
            const int k2 = j * 32 + lane;
            if (j < 9 || lane == 0) {
                int n = (k2 * 241) >> 12;
                int m = k2 - n * NNODE;
                sm.Ah[n * AHSTR + m] = (n == m) ? rbuf[j] + 1.0f : rbuf[j];
            }
        }
        const float xs = rxs;

        if (it < 7) {
            const size_t aoffn = (size_t)(item + 8) * (NNODE * NNODE);
            #pragma unroll
            for (int j = 0; j < 9; ++j) rbuf[j] = ntload(&adj[aoffn + j * 32 + lane]);
            rbuf[9] = (lane == 0) ? ntload(&adj[aoffn + 288]) : 0.f;
            rxs = (lane < NNODE) ? ntload(&x_str[(size_t)(item + 8) * NNODE + lane]) : 0.f;
        }

        float row[NNODE];
        float di = 0.f;
        if (lane < NNODE) {
            const float4* rp = reinterpret_cast<const float4*>(&sm.Ah[lane * AHSTR]);
            float4 a0 = rp[0], a1 = rp[1], a2 = rp[2], a3 = rp[3];
            row[0]=a0.x; row[1]=a0.y; row[2]=a0.z; row[3]=a0.w;
            row[4]=a1.x; row[5]=a1.y; row[6]=a1.z; row[7]=a1.w;
            row[8]=a2.x; row[9]=a2.y; row[10]=a2.z; row[11]=a2.w;
            row[12]=a3.x; row[13]=a3.y; row[14]=a3.z; row[15]=a3.w;
            row[16] = sm.Ah[lane * AHSTR + 16];
            float d = 0.f;
            #pragma unroll
            for (int m = 0; m < NNODE; ++m) d += row[m];
            di = (d > 0.f) ? rsqrtf(d) : 0.f;
            sm.dinv[lane] = di;
            sm.xd[lane]   = di * xs;
        }
        if (lane < NNODE) {
            const float4* xp = reinterpret_cast<const float4*>(sm.xd);
            float4 x0 = xp[0], x1 = xp[1], x2 = xp[2], x3 = xp[3];
            float a;
            a  = row[0]*x0.x + row[1]*x0.y + row[2]*x0.z + row[3]*x0.w;
            a += row[4]*x1.x + row[5]*x1.y + row[6]*x1.z + row[7]*x1.w;
            a += row[8]*x2.x + row[9]*x2.y + row[10]*x2.z + row[11]*x2.w;
            a += row[12]*x3.x + row[13]*x3.y + row[14]*x3.z + row[15]*x3.w;
            a += row[16] * sm.xd[16];
            sm.ag[lane] = a * di;
        }
        float h1d[NNODE];
        {
            const float4* dp = reinterpret_cast<const float4*>(sm.dinv);
            const float4* ap = reinterpret_cast<const float4*>(sm.ag);
            float dv[NNODE], av[NNODE];
            #pragma unroll
            for (int q = 0; q < 4; ++q) {
                float4 d4 = dp[q], a4 = ap[q];
                dv[4*q]=d4.x; dv[4*q+1]=d4.y; dv[4*q+2]=d4.z; dv[4*q+3]=d4.w;
                av[4*q]=a4.x; av[4*q+1]=a4.y; av[4*q+2]=a4.z; av[4*q+3]=a4.w;
            }
            dv[16] = sm.dinv[16]; av[16] = sm.ag[16];
            #pragma unroll
            for (int m = 0; m < NNODE; ++m) {
                float a = av[m] * W1o + b1o;
                h1d[m] = dv[m] * elu(a);
            }
        }
        {
            uint2* hw2 = reinterpret_cast<uint2*>(&sm.h1dT[lane * H1STR]);
            #pragma unroll
            for (int p = 0; p < 4; ++p) {
                uint2 v;
                v.x = pack2(h1d[4 * p],     h1d[4 * p + 1]);
                v.y = pack2(h1d[4 * p + 2], h1d[4 * p + 3]);
                hw2[p] = v;
            }
            reinterpret_cast<short*>(sm.h1dT)[lane * H1STR + 16] = bf16s(h1d[16]);
        }
        {
            const float4* rp16 = reinterpret_cast<const float4*>(&sm.Ah[16 * AHSTR]);
            float4 b0 = rp16[0], b1v = rp16[1], b2v = rp16[2], b3 = rp16[3];
            float a16;
            a16  = b0.x*h1d[0]  + b0.y*h1d[1]  + b0.z*h1d[2]  + b0.w*h1d[3];
            a16 += b1v.x*h1d[4] + b1v.y*h1d[5] + b1v.z*h1d[6] + b1v.w*h1d[7];
            a16 += b2v.x*h1d[8] + b2v.y*h1d[9] + b2v.z*h1d[10]+ b2v.w*h1d[11];
            a16 += b3.x*h1d[12] + b3.y*h1d[13] + b3.z*h1d[14] + b3.w*h1d[15];
            a16 += sm.Ah[16 * AHSTR + 16] * h1d[16];
            reinterpret_cast<short*>(sm.g)[16 * H1STR + lane] =
                bf16s(a16 * sm.dinv[16]);
        }

        #pragma unroll
        for (int i = 0; i < 2; ++i) {
            SlotB& si = sa[2 * w + i];
            const float dn = si.dinv[col];
            short8v ah;
            if (grp < 3) {
                float4 f0 = *reinterpret_cast<const float4*>(&si.Ah[col * AHSTR + grp * 8]);
                float4 f1 = *reinterpret_cast<const float4*>(&si.Ah[col * AHSTR + grp * 8 + 4]);
                float vv[8] = {f0.x, f0.y, f0.z, f0.w, f1.x, f1.y, f1.z, f1.w};
                #pragma unroll
                for (int j = 0; j < 8; ++j) ah[j] = bf16s(dn * vv[j]);
            } else {
                #pragma unroll
                for (int j = 0; j < 8; ++j) ah[j] = 0;
            }
            #pragma unroll
            for (int h = 0; h < 2; ++h) {
                short8v bq = *reinterpret_cast<const short8v*>(
                    &si.h1dT[(col + 16 * h) * H1STR + grp * 8]);
                f32x4 c = {0.f, 0.f, 0.f, 0.f};
                c = __builtin_amdgcn_mfma_f32_16x16x32_bf16(ah, bq, c, 0, 0, 0);
                #pragma unroll
                for (int r = 0; r < 4; ++r) {
                    reinterpret_cast<short*>(si.g)[(grp * 4 + r) * H1STR + col + 16 * h] =
                        bf16s(c[r]);
                }
            }
        }

        #pragma unroll
        for (int i = 0; i < 2; ++i) {
            const int itm = base + it * 8 + 2 * w + i;
            short8v a = *reinterpret_cast<const short8v*>(
                &sa[2 * w + i].g[col * H1STR + grp * 8]);
            f32x4 c0 = {b2c0, b2c0, b2c0, b2c0};
            f32x4 c1 = {b2c1, b2c1, b2c1, b2c1};
            c0 = __builtin_amdgcn_mfma_f32_16x16x32_bf16(a, wh0, c0, 0, 0, 0);
            c0 = __builtin_amdgcn_mfma_f32_16x16x32_bf16(a, wl0, c0, 0, 0, 0);
            c1 = __builtin_amdgcn_mfma_f32_16x16x32_bf16(a, wh1, c1, 0, 0, 0);
            c1 = __builtin_amdgcn_mfma_f32_16x16x32_bf16(a, wl1, c1, 0, 0, 0);
            #pragma unroll
            for (int r = 0; r < 4; ++r) {
                float h0 = elu(c0[r]);
                float h1 = elu(c1[r]);
                const size_t ob = (size_t)itm * 544 + (grp * 4 + r) * 32 + col;
                h2g[ob]      = __float2bfloat16(h0);
                h2g[ob + 16] = __float2bfloat16(h1);
                s4[r] += h0 + h1;
                q4[r] += h0 * h0 + h1 * h1;
            }
        }
        {
            const int ii = (l64 & 15) & 1;
            short8v a = *reinterpret_cast<const short8v*>(
                &sa[2 * w + ii].g[16 * H1STR + grp * 8]);
            f32x4 c0 = {b2c0, b2c0, b2c0, b2c0};
            f32x4 c1 = {b2c1, b2c1, b2c1, b2c1};
            c0 = __builtin_amdgcn_mfma_f32_16x16x32_bf16(a, wh0, c0, 0, 0, 0);
            c0 = __builtin_amdgcn_mfma_f32_16x16x32_bf16(a, wl0, c0, 0, 0, 0);
            c1 = __builtin_amdgcn_mfma_f32_16x16x32_bf16(a, wh1, c1, 0, 0, 0);
            c1 = __builtin_amdgcn_mfma_f32_16x16x32_bf16(a, wl1, c1, 0, 0, 0);
            if (grp == 0) {
                #pragma unroll
                for (int r = 0; r < 2; ++r) {
                    float h0 = elu(c0[r]);
                    float h1 = elu(c1[r]);
                    const size_t ob =
                        (size_t)(base + it * 8 + 2 * w + r) * 544 + 16 * 32 + col;
                    h2g[ob]      = __float2bfloat16(h0);
                    h2g[ob + 16] = __float2bfloat16(h1);
                    s16 += h0 + h1;
                    q16 += h0 * h0 + h1 * h1;
                }
            }
        }
    }

    #pragma unroll
    for (int m = 1; m <= 8; m <<= 1) {
        #pragma unroll
        for (int r = 0; r < 4; ++r) {
            s4[r] += __shfl_xor(s4[r], m, 64);
            q4[r] += __shfl_xor(q4[r], m, 64);
        }
        s16 += __shfl_xor(s16, m, 64);
        q16 += __shfl_xor(q16, m, 64);
    }
    if ((l64 & 15) == 0) {
        #pragma unroll
        for (int r = 0; r < 4; ++r) {
            const int n = grp * 4 + r;
            statb[w * 34 + n]         = s4[r];
            statb[w * 34 + NNODE + n] = q4[r];
        }
        if (grp == 0) {
            statb[w * 34 + 16]         = s16;
            statb[w * 34 + NNODE + 16] = q16;
        }
    }
    __syncthreads();
    if (tid < 34) {
        float s = statb[tid] + statb[34 + tid] + statb[68 + tid] + statb[102 + tid];
        unsafeAtomicAdd(&gstat[tid], s);
    }
}

// ---------------------------------------------------------------- PASS 2 (R12: MFMA head, low-LDS)
__global__ __launch_bounds__(256) void pass2_kernel(
    const __hip_bfloat16* __restrict__ h2g,
    const float* __restrict__ x_raw, const float* __restrict__ x_cov,
    const float* __restrict__ age,
    const float* __restrict__ gamma, const float* __restrict__ beta,
    const float* __restrict__ Wr1, const float* __restrict__ br1,
    const float* __restrict__ Wr2, const float* __restrict__ br2,
    const float* __restrict__ Wr3, const float* __restrict__ br3,
    const float* __restrict__ gstat, float* __restrict__ out)
{
    __shared__ short8v wf1[8][64];
    __shared__ short8v wf2[8][64];
    __shared__ __hip_bfloat16 zl[4][64 * ZSTR];
    __shared__ float   s17[18];

    const int tid = threadIdx.x;
    const int w   = tid >> 6;
    const int l   = tid & 63;
    const int col = l & 15;
    const int g   = l >> 4;
    const int ibase = blockIdx.x * 64;
    const int wb    = ibase + w * 16;
    const int item  = wb + col;

    if (tid == 0) {
        const float invBH = 1.0f / ((float)BTOT * (float)HH);
        float Cs = 0.f;
        #pragma unroll
        for (int n = 0; n < NNODE; ++n) {
            float mean = gstat[n] * invBH;
            float var  = gstat[NNODE + n] * invBH - mean * mean;
            float sc   = gamma[n] * rsqrtf(var + 1e-5f);
            s17[n] = sc * (1.0f / (float)NNODE);
            Cs += beta[n] - mean * sc;
        }
        s17[NNODE] = Cs * (1.0f / (float)NNODE);
    }

    for (int idx = tid; idx < 8 * 64; idx += 256) {
        int fid = idx >> 6, tl = idx & 63;
        int kst = fid >> 2, nt = fid & 3;
        int tc = tl & 15, tg = tl >> 4;
        short8v v;
        #pragma unroll
        for (int j = 0; j < 8; ++j) {
            int k = kst * 32 + tg * 8 + j;
            float f = (k < 53) ? Wr1[k * 64 + nt * 16 + tc] : 0.f;
            v[j] = bf16s(f);
        }
        wf1[fid][tl] = v;
    }
    for (int idx = tid; idx < 8 * 64; idx += 256) {
        int fid = idx >> 6, tl = idx & 63;
        int kst = fid >> 2, mt = (fid >> 1) & 1, hl = fid & 1;
        int tc = tl & 15, tg = tl >> 4;
        short8v v;
        #pragma unroll
        for (int j = 0; j < 8; ++j) {
            int k = kst * 32 + tg * 8 + j;
            float f = Wr2[k * 32 + mt * 16 + tc];
            v[j] = hl ? bf16s(f - bfround(f)) : bf16s(f);
        }
        wf2[fid][tl] = v;
    }
    __syncthreads();

    float emb[8];
    const float cst = s17[NNODE];
    #pragma unroll
    for (int j = 0; j < 8; ++j) emb[j] = cst;
    const __hip_bfloat16* hp = h2g + (size_t)item * 544 + g * 8;
    #pragma unroll
    for (int n = 0; n < NNODE; ++n) {
        uint4 v = *reinterpret_cast<const uint4*>(hp + n * 32);
        float sn = s17[n];
        emb[0] += sn * blo(v.x); emb[1] += sn * bhi(v.x);
        emb[2] += sn * blo(v.y); emb[3] += sn * bhi(v.y);
        emb[4] += sn * blo(v.z); emb[5] += sn * bhi(v.z);
        emb[6] += sn * blo(v.w); emb[7] += sn * bhi(v.w);
    }

    float tail[8];
    if (g < 2) {
        const float* xr = x_raw + (size_t)item * 17 + g * 8;
        #pragma unroll
        for (int j = 0; j < 8; ++j) tail[j] = xr[j];
    } else if (g == 2) {
        tail[0] = x_raw[(size_t)item * 17 + 16];
        tail[1] = x_cov[(size_t)item * 3 + 0];
        tail[2] = x_cov[(size_t)item * 3 + 1];
        tail[3] = x_cov[(size_t)item * 3 + 2];
        tail[4] = age[item];
        tail[5] = 0.f; tail[6] = 0.f; tail[7] = 0.f;
    } else {
        #pragma unroll
        for (int j = 0; j < 8; ++j) tail[j] = 0.f;
    }

    short8v a0h, a0l, a1h, a1l;
    #pragma unroll
    for (int j = 0; j < 8; ++j) {
        float f = emb[j];
        a0h[j] = bf16s(f); a0l[j] = bf16s(f - bfround(f));
        float f1 = tail[j];
        a1h[j] = bf16s(f1); a1l[j] = bf16s(f1 - bfround(f1));
    }

    f32x4 C1[4];
    #pragma unroll
    for (int nt = 0; nt < 4; ++nt) {
        float b = br1[nt * 16 + col];
        C1[nt] = (f32x4){b, b, b, b};
        C1[nt] = __builtin_amdgcn_mfma_f32_16x16x32_bf16(a0h, wf1[nt    ][l], C1[nt], 0, 0, 0);
        C1[nt] = __builtin_amdgcn_mfma_f32_16x16x32_bf16(a0l, wf1[nt    ][l], C1[nt], 0, 0, 0);
        C1[nt] = __builtin_amdgcn_mfma_f32_16x16x32_bf16(a1h, wf1[4 + nt][l], C1[nt], 0, 0, 0);
        C1[nt] = __builtin_amdgcn_mfma_f32_16x16x32_bf16(a1l, wf1[4 + nt][l], C1[nt], 0, 0, 0);
    }
    #pragma unroll
    for (int nt = 0; nt < 4; ++nt) {
        uint2 v;
        v.x = pack2(fmaxf(C1[nt][0], 0.f), fmaxf(C1[nt][1], 0.f));
        v.y = pack2(fmaxf(C1[nt][2], 0.f), fmaxf(C1[nt][3], 0.f));
        *reinterpret_cast<uint2*>(&zl[w][(nt * 16 + col) * ZSTR + g * 4]) = v;
    }

    f32x4 C2[2];
    #pragma unroll
    for (int mt = 0; mt < 2; ++mt)
        C2[mt] = (f32x4){br2[mt*16 + g*4], br2[mt*16 + g*4 + 1],
                         br2[mt*16 + g*4 + 2], br2[mt*16 + g*4 + 3]};
    #pragma unroll
    for (int kst = 0; kst < 2; ++kst) {
        short8v bh;
        #pragma unroll
        for (int j = 0; j < 8; ++j)
            bh[j] = reinterpret_cast<const short*>(zl[w])[(kst * 32 + g * 8 + j) * ZSTR + col];
        #pragma unroll
        for (int mt = 0; mt < 2; ++mt) {
            C2[mt] = __builtin_amdgcn_mfma_f32_16x16x32_bf16(wf2[kst*4 + mt*2    ][l], bh, C2[mt], 0, 0, 0);
            C2[mt] = __builtin_amdgcn_mfma_f32_16x16x32_bf16(wf2[kst*4 + mt*2 + 1][l], bh, C2[mt], 0, 0, 0);
        }
    }

    float sum = 0.f;
    #pragma unroll
    for (int mt = 0; mt < 2; ++mt)
        #pragma unroll
        for (int r = 0; r < 4; ++r)
            sum += fmaxf(C2[mt][r], 0.f) * Wr3[mt * 16 + g * 4 + r];
    sum += __shfl_xor(sum, 16, 64);
    sum += __shfl_xor(sum, 32, 64);
    if (l < 16)
        out[wb + l] = 1.0f / (1.0f + __expf(-(sum + br3[0])));
}

// ---------------------------------------------------------------- fallback (round-0, passing)
struct __align__(16) SlotMem {
    float Ah[NNODE][20];
    float dinv[20];
    float xd[20];
    float ex[32];
    float c[56];
    float z[64];
};

template<int PASS>
__global__ __launch_bounds__(256) void gcn_fb_kernel(
    const float* __restrict__ x_str, const float* __restrict__ x_raw,
    const float* __restrict__ adj,   const float* __restrict__ x_cov,
    const float* __restrict__ age,
    const float* __restrict__ W1, const float* __restrict__ b1,
    const float* __restrict__ W2, const float* __restrict__ b2,
    const float* __restrict__ gamma, const float* __restrict__ beta,
    const float* __restrict__ Wr1, const float* __restrict__ br1,
    const float* __restrict__ Wr2, const float* __restrict__ br2,
    const float* __restrict__ Wr3, const float* __restrict__ br3,
    float* __restrict__ gstat, float* __restrict__ out)
{
    __shared__ SlotMem slots[8];
    __shared__ __align__(16) float hw[(PASS == 2) ? 5504 : 1];
    __shared__ float s17[(PASS == 2) ? 18 : 1];
    __shared__ float statb[(PASS == 1) ? 4 * 34 : 1];

    const int tid  = threadIdx.x;
    const int slot = tid >> 5;
    const int lane = tid & 31;
    SlotMem& sm = slots[slot];

    const float W1o = W1[lane];
    const float b1o = b1[lane];
    const float b2o = b2[lane];
    float W2col[HH];
    #pragma unroll
    for (int k = 0; k < HH; ++k) W2col[k] = W2[k * HH + lane];

    float Wr3o = 0.f, br2o = 0.f, br3v = 0.f;
    if constexpr (PASS == 2) {
        Wr3o = Wr3[lane];
        br2o = br2[lane];
        br3v = br3[0];
        for (int t = tid; t < 5504; t += 256) {
            float v;
            if (t < 3392) {
                int i = t >> 6, r = t & 63;
                v = Wr1[i * 64 + ((r & 1) << 5) + (r >> 1)];
            } else if (t < 3456) {
                v = br1[t - 3392];
            } else {
                v = Wr2[t - 3456];
            }
            hw[t] = v;
        }
        if (tid == 0) {
            const float invBH = 1.0f / ((float)BTOT * (float)HH);
            float Cs = 0.f;
            #pragma unroll
            for (int n = 0; n < NNODE; ++n) {
                float mean = gstat[n] * invBH;
                float var  = gstat[NNODE + n] * invBH - mean * mean;
                float sc   = gamma[n] * rsqrtf(var + 1e-5f);
                s17[n] = sc * (1.0f / (float)NNODE);
                Cs += beta[n] - mean * sc;
            }
            s17[NNODE] = Cs * (1.0f / (float)NNODE);
        }
        __syncthreads();
    }

    float psum[NNODE], psq[NNODE];
    if constexpr (PASS == 1) {
        #pragma unroll
        for (int n = 0; n < NNODE; ++n) { psum[n] = 0.f; psq[n] = 0.f; }
    }

    const int base = blockIdx.x * 64;
    for (int it = 0; it < 8; ++it) {
        const int item = base + it * 8 + slot;
        const size_t aoff = (size_t)item * (NNODE * NNODE);

        for (int k = lane; k < NNODE * NNODE; k += 32) {
            int n = k / NNODE;
            int m = k - n * NNODE;
            float v = adj[aoff + k];
            if (n == m) v += 1.0f;
            sm.Ah[n][m] = v;
        }
        float xs = 0.f;
        if (lane < NNODE) xs = x_str[(size_t)item * NNODE + lane];
        if (lane < NNODE) {
            float d = 0.f;
            #pragma unroll
            for (int m = 0; m < NNODE; ++m) d += sm.Ah[lane][m];
            float di = (d > 0.f) ? rsqrtf(d) : 0.f;
            sm.dinv[lane] = di;
            sm.xd[lane]   = di * xs;
        }
        if (lane < NNODE) {
            float a = 0.f;
            #pragma unroll
            for (int m = 0; m < NNODE; ++m) a += sm.Ah[lane][m] * sm.xd[m];
            sm.ex[lane] = a * sm.dinv[lane];
        }
        float h1d[NNODE];
        #pragma unroll
        for (int m = 0; m < NNODE; ++m) {
            float a = sm.ex[m] * W1o + b1o;
            float h = (a > 0.f) ? a : (__expf(a) - 1.0f);
            h1d[m] = sm.dinv[m] * h;
        }

        float emb = 0.f;
        for (int n = 0; n < NNODE; ++n) {
            const float4* rowv = reinterpret_cast<const float4*>(sm.Ah[n]);
            float4 r0 = rowv[0], r1 = rowv[1], r2 = rowv[2], r3 = rowv[3];
            float acc;
            acc  = r0.x*h1d[0]  + r0.y*h1d[1]  + r0.z*h1d[2]  + r0.w*h1d[3];
            acc += r1.x*h1d[4]  + r1.y*h1d[5]  + r1.z*h1d[6]  + r1.w*h1d[7];
            acc += r2.x*h1d[8]  + r2.y*h1d[9]  + r2.z*h1d[10] + r2.w*h1d[11];
            acc += r3.x*h1d[12] + r3.y*h1d[13] + r3.z*h1d[14] + r3.w*h1d[15];
            acc += sm.Ah[n][16] * h1d[16];
            float a2 = acc * sm.dinv[n];
            sm.ex[lane] = a2;
            const float4* exv = reinterpret_cast<const float4*>(sm.ex);
            float hacc = b2o;
            #pragma unroll
            for (int q = 0; q < 8; ++q) {
                float4 e = exv[q];
                hacc += e.x * W2col[4*q]   + e.y * W2col[4*q+1]
                      + e.z * W2col[4*q+2] + e.w * W2col[4*q+3];
            }
            float h2 = (hacc > 0.f) ? hacc : (__expf(hacc) - 1.0f);
            if constexpr (PASS == 1) {
                psum[n] += h2;
                psq[n]  += h2 * h2;
            } else {
                emb += s17[n] * h2;
            }
        }

        if constexpr (PASS == 2) {
            emb += s17[NNODE];
            sm.c[lane] = emb;
            if (lane < NNODE) sm.c[HH + lane] = x_raw[(size_t)item * NNODE + lane];
            if (lane < 3)     sm.c[49 + lane] = x_cov[(size_t)item * 3 + lane];
            if (lane == 0)    sm.c[52] = age[item];
            float a1 = hw[3392 + lane];
            float a2h = hw[3392 + 32 + lane];
            for (int i = 0; i < 52; i += 4) {
                float4 cv = *reinterpret_cast<const float4*>(&sm.c[i]);
                #pragma unroll
                for (int u = 0; u < 4; ++u) {
                    float cu = (&cv.x)[u];
                    float2 w2 = *reinterpret_cast<const float2*>(&hw[(i + u) * 64 + lane * 2]);
                    a1  += cu * w2.x;
                    a2h += cu * w2.y;
                }
            }
            {
                float cu = sm.c[52];
                float2 w2 = *reinterpret_cast<const float2*>(&hw[52 * 64 + lane * 2]);
                a1 += cu * w2.x; a2h += cu * w2.y;
            }
            a1 = fmaxf(a1, 0.f); a2h = fmaxf(a2h, 0.f);
            sm.z[lane] = a1;
            sm.z[32 + lane] = a2h;
            float acc = br2o;
            for (int i = 0; i < 64; i += 4) {
                float4 zv = *reinterpret_cast<const float4*>(&sm.z[i]);
                #pragma unroll
                for (int u = 0; u < 4; ++u)
                    acc += (&zv.x)[u] * hw[3456 + (i + u) * 32 + lane];
            }
            acc = fmaxf(acc, 0.f);
            float v = acc * Wr3o;
            v += __shfl_xor(v, 16, 32);
            v += __shfl_xor(v, 8, 32);
            v += __shfl_xor(v, 4, 32);
            v += __shfl_xor(v, 2, 32);
            v += __shfl_xor(v, 1, 32);
            if (lane == 0) {
                float s = v + br3v;
                out[item] = 1.0f / (1.0f + __expf(-s));
            }
        }
    }

    if constexpr (PASS == 1) {
        #pragma unroll
        for (int n = 0; n < NNODE; ++n) {
            float a = psum[n], b = psq[n];
            #pragma unroll
            for (int m = 32; m >= 1; m >>= 1) {
                a += __shfl_xor(a, m, 64);
                b += __shfl_xor(b, m, 64);
            }
            psum[n] = a; psq[n] = b;
        }
        const int wv = tid >> 6;
        if ((tid & 63) == 0) {
            #pragma unroll
            for (int n = 0; n < NNODE; ++n) {
                statb[wv * 34 + n]         = psum[n];
                statb[wv * 34 + NNODE + n] = psq[n];
            }
        }
        __syncthreads();
        if (tid < 34) {
            float s = statb[tid] + statb[34 + tid] + statb[68 + tid] + statb[102 + tid];
            unsafeAtomicAdd(&gstat[tid], s);
        }
    }
}

extern "C" void kernel_launch(void* const* d_in, const int* in_sizes, int n_in,
                              void* d_out, int out_size, void* d_ws, size_t ws_size,
                              hipStream_t stream) {
    (void)in_sizes; (void)n_in; (void)out_size;
    const float* x_str = (const float*)d_in[0];
    const float* x_raw = (const float*)d_in[1];
    const float* adj   = (const float*)d_in[2];
    const float* x_cov = (const float*)d_in[3];
    const float* age   = (const float*)d_in[4];
    const float* W1    = (const float*)d_in[5];
    const float* b1    = (const float*)d_in[6];
    const float* W2    = (const float*)d_in[7];
    const float* b2    = (const float*)d_in[8];
    const float* gamma = (const float*)d_in[9];
    const float* beta  = (const float*)d_in[10];
    const float* Wr1   = (const float*)d_in[11];
    const float* br1   = (const float*)d_in[12];
    const float* Wr2   = (const float*)d_in[13];
    const float* br2   = (const float*)d_in[14];
    const float* Wr3   = (const float*)d_in[15];
    const float* br3   = (const float*)d_in[16];
    float* gstat = (float*)d_ws;
    float* out   = (float*)d_out;

    const size_t need = 256 + (size_t)BTOT * 544 * 2;
    hipMemsetAsync(d_ws, 0, 34 * sizeof(float), stream);
    if (ws_size >= need) {
        __hip_bfloat16* h2g = (__hip_bfloat16*)((char*)d_ws + 256);
        pass1_kernel<<<2048, 256, 0, stream>>>(x_str, adj, W1, b1, W2, b2, h2g, gstat);
        pass2_kernel<<<2048, 256, 0, stream>>>(h2g, x_raw, x_cov, age, gamma, beta,
            Wr1, br1, Wr2, br2, Wr3, br3, gstat, out);
    } else {
        gcn_fb_kernel<1><<<2048, 256, 0, stream>>>(x_str, x_raw, adj, x_cov, age,
            W1, b1, W2, b2, gamma, beta, Wr1, br1, Wr2, br2, Wr3, br3, gstat, out);
        gcn_fb_kernel<2><<<2048, 256, 0, stream>>>(x_str, x_raw, adj, x_cov, age,
            W1, b1, W2, b2, gamma, beta, Wr1, br1, Wr2, br2, Wr3, br3, gstat, out);
    }
}